// Round 1
// baseline (118.575 us; speedup 1.0000x reference)
//
#include <hip/hip_runtime.h>
#include <math.h>

#define BB 4
#define LL 1024
#define DD 1024
#define KK 20
#define CC 21

__device__ __forceinline__ float wave_reduce_sum(float v) {
    #pragma unroll
    for (int off = 1; off < 64; off <<= 1)
        v += __shfl_xor(v, off, 64);
    return v;
}

// ---------------------------------------------------------------------------
// Kernel 0: zd[k,c] = dic[k,:] . Wz_w[c,:] + Wz_b[c]       (e in [0,420))
//           M [k,c] = dic[k,:] . cs_w[c, D:2D]             (e in [420,840))
// one wave per entry
// ---------------------------------------------------------------------------
__global__ __launch_bounds__(64) void k0_zdM(
    const float* __restrict__ dic,
    const float* __restrict__ Wz_w, const float* __restrict__ Wz_b,
    const float* __restrict__ cs_w,
    float* __restrict__ zd, float* __restrict__ M)
{
    int e = blockIdx.x;                 // 0..2*K*C-1
    int lane = threadIdx.x;
    bool isM = (e >= KK * CC);
    int e2 = isM ? e - KK * CC : e;
    int k = e2 / CC, c = e2 % CC;
    const float* a = dic + k * DD;
    const float* w = isM ? (cs_w + (size_t)c * (2 * DD) + DD) : (Wz_w + c * DD);
    float p = 0.f;
    #pragma unroll
    for (int i = 0; i < DD / 64; ++i) {
        int d = lane + 64 * i;
        p += a[d] * w[d];
    }
    p = wave_reduce_sum(p);
    if (lane == 0) {
        if (isM) M[e2] = p;
        else     zd[e2] = p + Wz_b[c];
    }
}

// ---------------------------------------------------------------------------
// Kernel 1: per row r = b*L + l  (one wave per row)
//   yW[c] = y . Wy_w[c,:] + Wy_b[c]
//   ly[c] = y . cs_w[c, :D]
//   s[k]  = scale * sum_c yW[c] * zd[k,c] ; att = softmax_k(s)
//   w[k]  = att[k] * prior[k]
//   lz[c] = sum_k w[k] * M[k,c] + cs_b[c]
//   store ly, lz to workspace
// ---------------------------------------------------------------------------
__global__ __launch_bounds__(64) void k1_rows(
    const float* __restrict__ x,
    const float* __restrict__ prior,
    const float* __restrict__ Wy_w, const float* __restrict__ Wy_b,
    const float* __restrict__ cs_w, const float* __restrict__ cs_b,
    const float* __restrict__ zd, const float* __restrict__ M,
    float* __restrict__ ly_ws, float* __restrict__ lz_ws)
{
    int r = blockIdx.x;                 // 0..B*L-1
    int lane = threadIdx.x;

    __shared__ float zds[KK * CC];
    __shared__ float Ms[KK * CC];
    for (int i = lane; i < KK * CC; i += 64) {
        zds[i] = zd[i];
        Ms[i]  = M[i];
    }

    const float* y = x + (size_t)r * DD;
    float yv[DD / 64];
    #pragma unroll
    for (int i = 0; i < DD / 64; ++i) yv[i] = y[lane + 64 * i];

    __syncthreads();

    float yw[CC], lyv[CC];
    #pragma unroll
    for (int c = 0; c < CC; ++c) {
        const float* w1 = Wy_w + c * DD;
        const float* w2 = cs_w + (size_t)c * (2 * DD);     // first half
        float p1 = 0.f, p2 = 0.f;
        #pragma unroll
        for (int i = 0; i < DD / 64; ++i) {
            int d = lane + 64 * i;
            p1 += yv[i] * w1[d];
            p2 += yv[i] * w2[d];
        }
        yw[c]  = wave_reduce_sum(p1) + Wy_b[c];
        lyv[c] = wave_reduce_sum(p2);
    }

    // logits + softmax over K (redundant on all lanes — trivially cheap)
    const float scale = 0.2182178902359924f;   // 1/sqrt(21)
    float s[KK];
    float m = -1e30f;
    #pragma unroll
    for (int k = 0; k < KK; ++k) {
        float t = 0.f;
        #pragma unroll
        for (int c = 0; c < CC; ++c) t += yw[c] * zds[k * CC + c];
        s[k] = t * scale;
        m = fmaxf(m, s[k]);
    }
    float sum = 0.f;
    #pragma unroll
    for (int k = 0; k < KK; ++k) { s[k] = expf(s[k] - m); sum += s[k]; }
    float inv = 1.f / sum;
    float wk[KK];
    #pragma unroll
    for (int k = 0; k < KK; ++k) wk[k] = s[k] * inv * prior[k];

    float lzv[CC];
    #pragma unroll
    for (int c = 0; c < CC; ++c) {
        float t = cs_b[c];
        #pragma unroll
        for (int k = 0; k < KK; ++k) t += wk[k] * Ms[k * CC + c];
        lzv[c] = t;
    }

    if (lane == 0) {
        float* lyp = ly_ws + (size_t)r * CC;
        float* lzp = lz_ws + (size_t)r * CC;
        #pragma unroll
        for (int c = 0; c < CC; ++c) { lyp[c] = lyv[c]; lzp[c] = lzv[c]; }
    }
}

// ---------------------------------------------------------------------------
// Kernel 2: the 352 MB outer-sum write.
//   block = (b, i); out[blk*L*C + n] = lz[b*L*C + n] + ly[blk*C + n%21]
//   n walks lz[b] in its own flat layout -> coalesced float4 stream.
// ---------------------------------------------------------------------------
__global__ __launch_bounds__(256) void k2_outer(
    const float* __restrict__ ly_ws, const float* __restrict__ lz_ws,
    float* __restrict__ out)
{
    int blk = blockIdx.x;               // b*L + i
    int b = blk >> 10;                  // / L
    int tid = threadIdx.x;

    __shared__ float lys[CC];
    if (tid < CC) lys[tid] = ly_ws[(size_t)blk * CC + tid];
    __syncthreads();

    const float* lzp = lz_ws + (size_t)b * LL * CC;
    float* op = out + (size_t)blk * (LL * CC);

    // L*C = 21504 floats = 5376 float4 = 21 iters * 256 threads
    #pragma unroll
    for (int t = 0; t < 21; ++t) {
        int idx = t * 256 + tid;
        int n = idx * 4;
        float4 lz4 = *reinterpret_cast<const float4*>(lzp + n);
        int c0 = n % 21;
        int c1 = c0 + 1; if (c1 == 21) c1 = 0;
        int c2 = c1 + 1; if (c2 == 21) c2 = 0;
        int c3 = c2 + 1; if (c3 == 21) c3 = 0;
        float4 o;
        o.x = lz4.x + lys[c0];
        o.y = lz4.y + lys[c1];
        o.z = lz4.z + lys[c2];
        o.w = lz4.w + lys[c3];
        *reinterpret_cast<float4*>(op + n) = o;
    }
}

extern "C" void kernel_launch(void* const* d_in, const int* in_sizes, int n_in,
                              void* d_out, int out_size, void* d_ws, size_t ws_size,
                              hipStream_t stream)
{
    const float* x     = (const float*)d_in[0];
    const float* dic   = (const float*)d_in[1];
    const float* prior = (const float*)d_in[2];
    const float* Wy_w  = (const float*)d_in[3];
    const float* Wy_b  = (const float*)d_in[4];
    const float* Wz_w  = (const float*)d_in[5];
    const float* Wz_b  = (const float*)d_in[6];
    const float* cs_w  = (const float*)d_in[7];
    const float* cs_b  = (const float*)d_in[8];
    float* out = (float*)d_out;

    float* ws = (float*)d_ws;
    float* zd = ws;                       // 420 floats
    float* M  = ws + 512;                 // 420 floats
    float* ly = ws + 1024;                // B*L*C = 86016 floats
    float* lz = ly + BB * LL * CC;        // 86016 floats

    k0_zdM <<<dim3(2 * KK * CC), dim3(64), 0, stream>>>(dic, Wz_w, Wz_b, cs_w, zd, M);
    k1_rows<<<dim3(BB * LL),     dim3(64), 0, stream>>>(x, prior, Wy_w, Wy_b, cs_w, cs_b,
                                                        zd, M, ly, lz);
    k2_outer<<<dim3(BB * LL),    dim3(256), 0, stream>>>(ly, lz, out);
}